// Round 1
// baseline (2594.823 us; speedup 1.0000x reference)
//
#include <hip/hip_runtime.h>

// ---------------- problem constants (match reference setup_inputs) ----------
#define NVOX 12000
#define NPTS 32
#define CIN  5
#define C1   64     // VFE1 out
#define C2   128    // VFE2 out
#define GD   16
#define GH   128
#define GW   128
#define SP   (GD*GH*GW)          // 262144 = 2^18
#define LOG_SP 18
static constexpr float EPSBN = 1e-5f;

// NOTE: biases (b1,b2,cb1..3) are mathematically no-ops: every linear/conv is
// immediately followed by training-mode BN which subtracts the per-channel
// mean, and a per-channel constant shifts mean but not variance. Skipped.

// ---------------- VFE1 stats: per-channel sum/sumsq of y = x@w1 over all rows
__global__ void vfe1_stats(const float* __restrict__ x, const float* __restrict__ w1,
                           float* __restrict__ sums) {
    __shared__ float s_w[CIN*C1];
    __shared__ float s_red[2][4][C1];
    int t = threadIdx.x; // 256
    for (int i = t; i < CIN*C1; i += 256) s_w[i] = w1[i];
    __syncthreads();
    int ch = t & 63, rr = t >> 6;
    float sum = 0.f, sq = 0.f;
    const int NROWS = NVOX * NPTS; // 384000
    for (int row = blockIdx.x*4 + rr; row < NROWS; row += gridDim.x*4) {
        const float* xr = x + row*CIN;
        float y = 0.f;
        #pragma unroll
        for (int c = 0; c < CIN; ++c) y += xr[c] * s_w[c*C1 + ch];
        sum += y; sq += y*y;
    }
    s_red[0][rr][ch] = sum; s_red[1][rr][ch] = sq;
    __syncthreads();
    if (rr == 0) {
        sum = s_red[0][0][ch]+s_red[0][1][ch]+s_red[0][2][ch]+s_red[0][3][ch];
        sq  = s_red[1][0][ch]+s_red[1][1][ch]+s_red[1][2][ch]+s_red[1][3][ch];
        atomicAdd(&sums[ch], sum);
        atomicAdd(&sums[C1+ch], sq);
    }
}

// ---------------- generic BN finalize: sums -> (scale, shift) ----------------
__global__ void bn_finalize(const float* __restrict__ sums, const float* __restrict__ g,
                            const float* __restrict__ be, float* __restrict__ ss,
                            int C, float invN) {
    int c = blockIdx.x*blockDim.x + threadIdx.x;
    if (c >= C) return;
    float mean = sums[c]*invN;
    float var  = sums[C+c]*invN - mean*mean;
    float sc = g[c]*rsqrtf(var + EPSBN);
    ss[c] = sc; ss[C+c] = be[c] - mean*sc;
}

// ---------------- VFE1 apply: y=x@w1 -> BN -> relu -> max over 32 points ----
__global__ void vfe1_apply(const float* __restrict__ x, const float* __restrict__ w1,
                           const float* __restrict__ ss, float* __restrict__ f1) {
    __shared__ float s_w[CIN*C1];
    __shared__ float s_x[NPTS*CIN];
    int v = blockIdx.x, t = threadIdx.x; // 64 threads
    for (int i = t; i < CIN*C1; i += 64) s_w[i] = w1[i];
    for (int i = t; i < NPTS*CIN; i += 64) s_x[i] = x[v*NPTS*CIN + i];
    __syncthreads();
    float sc = ss[t], sh = ss[C1+t];
    float m = 0.f; // relu >= 0 so 0 is the identity for max(relu(.))
    for (int p = 0; p < NPTS; ++p) {
        float y = 0.f;
        #pragma unroll
        for (int c = 0; c < CIN; ++c) y += s_x[p*CIN+c]*s_w[c*C1+t];
        m = fmaxf(m, y*sc + sh);
    }
    f1[v*C1 + t] = m;
}

// ---------------- VFE2 linear + stats accumulation -----------------------
__global__ void vfe2_linear(const float* __restrict__ f1, const float* __restrict__ w2,
                            float* __restrict__ y2, float* __restrict__ sums) {
    __shared__ float s_w[C1*C2];   // 8192 floats = 32 KB
    __shared__ float s_f[16*C1];
    int t = threadIdx.x; // 128
    for (int i = t; i < C1*C2; i += 128) s_w[i] = w2[i];
    int v0 = blockIdx.x*16;
    for (int i = t; i < 16*C1; i += 128) s_f[i] = f1[v0*C1 + i];
    __syncthreads();
    float sum = 0.f, sq = 0.f;
    for (int vl = 0; vl < 16; ++vl) {
        float y = 0.f;
        #pragma unroll 8
        for (int c = 0; c < C1; ++c) y += s_f[vl*C1+c]*s_w[c*C2+t];
        y2[(v0+vl)*C2 + t] = y;
        sum += y; sq += y*y;
    }
    atomicAdd(&sums[t], sum);
    atomicAdd(&sums[C2+t], sq);
}

// ---------------- VFE2 apply (in place): BN -> relu ----------------------
__global__ void vfe2_apply(float* __restrict__ y2, const float* __restrict__ ss) {
    int i = blockIdx.x*blockDim.x + threadIdx.x;
    if (i >= NVOX*C2) return;
    int c = i & (C2-1);
    y2[i] = fmaxf(0.f, y2[i]*ss[c] + ss[C2+c]);
}

// ---------------- scatter: last-write-wins via max voxel index -----------
__global__ void scatter_winner(const int* __restrict__ coords, int* __restrict__ winner) {
    int v = blockIdx.x*blockDim.x + threadIdx.x;
    if (v >= NVOX) return;
    int d = coords[v*3+0], h = coords[v*3+1], w = coords[v*3+2];
    atomicMax(&winner[(d*GH + h)*GW + w], v);
}

// ---------------- densify: grid[c][z][y][x] ------------------------------
__global__ void build_grid(const int* __restrict__ winner, const float* __restrict__ f2,
                           float* __restrict__ grid) {
    const int total = C2*SP;
    for (int e = blockIdx.x*blockDim.x + threadIdx.x; e < total; e += gridDim.x*blockDim.x) {
        int c = e >> LOG_SP, s = e & (SP-1);
        int wn = winner[s];
        grid[e] = (wn >= 0) ? f2[wn*C2 + c] : 0.f;
    }
}

// ---------------- direct fp32 conv3d, stride 2, pad 1, k=3 ---------------
// block: 256 threads -> 64 co x 64 spatial (8x8), thread owns 4co x 4sp
template<int CI, int CO, int DI, int HI, int WI, int DO, int HO, int WO>
__global__ __launch_bounds__(256) void conv3d_s2(const float* __restrict__ in,
                                                 const float* __restrict__ wt,
                                                 float* __restrict__ out) {
    constexpr int CI_T = 4;
    constexpr int CO_T = 64;
    __shared__ float s_in[CI_T][3][17][17];     // 13.9 KB
    __shared__ float s_w[CI_T][27][CO_T];       // 27.6 KB
    const int nbx = WO/8, nby = HO/8;
    int b = blockIdx.x;
    int bx = b % nbx; b /= nbx;
    int by = b % nby; b /= nby;
    int bz = b % DO;  b /= DO;
    int co0 = b * CO_T;
    int ox0 = bx*8, oy0 = by*8;
    int t = threadIdx.x;
    int sp_g = t & 15;   // 16 groups x 4 sp (strided by 16) = 64 spatial
    int co_g = t >> 4;   // 16 groups x 4 co = 64 channels
    float acc[4][4] = {};
    for (int cib = 0; cib < CI/CI_T; ++cib) {
        __syncthreads();
        // stage input tile (with zero padding at borders)
        for (int l = t; l < CI_T*3*17*17; l += 256) {
            int ci = l / (3*17*17);
            int r  = l % (3*17*17);
            int zz = r / 289; int rr = r % 289;
            int yy = rr / 17, xx = rr % 17;
            int iz = 2*bz  - 1 + zz;
            int iy = 2*oy0 - 1 + yy;
            int ix = 2*ox0 - 1 + xx;
            float v = 0.f;
            if ((unsigned)iz < (unsigned)DI && (unsigned)iy < (unsigned)HI &&
                (unsigned)ix < (unsigned)WI)
                v = in[(((cib*CI_T+ci)*DI + iz)*HI + iy)*WI + ix];
            s_in[ci][zz][yy][xx] = v;
        }
        // stage weights as [ci][tap][co] so 4-co read is one ds_read_b128
        for (int l = t; l < CI_T*27*CO_T; l += 256) {
            int co  = l & (CO_T-1);
            int tap = (l >> 6) % 27;
            int ci  = (l >> 6) / 27;
            s_w[ci][tap][co] = wt[((co0+co)*CI + cib*CI_T + ci)*27 + tap];
        }
        __syncthreads();
        #pragma unroll
        for (int ci = 0; ci < CI_T; ++ci) {
            #pragma unroll
            for (int kz = 0; kz < 3; ++kz)
            #pragma unroll
            for (int ky = 0; ky < 3; ++ky)
            #pragma unroll
            for (int kx = 0; kx < 3; ++kx) {
                int tap = (kz*3+ky)*3+kx;
                float w0 = s_w[ci][tap][co_g*4+0];
                float w1 = s_w[ci][tap][co_g*4+1];
                float w2 = s_w[ci][tap][co_g*4+2];
                float w3 = s_w[ci][tap][co_g*4+3];
                #pragma unroll
                for (int k = 0; k < 4; ++k) {
                    int sp = sp_g + 16*k;
                    int oy = sp >> 3, ox = sp & 7;
                    float iv = s_in[ci][kz][2*oy+ky][2*ox+kx];
                    acc[0][k] += iv*w0; acc[1][k] += iv*w1;
                    acc[2][k] += iv*w2; acc[3][k] += iv*w3;
                }
            }
        }
    }
    #pragma unroll
    for (int j = 0; j < 4; ++j) {
        int co = co0 + co_g*4 + j;
        #pragma unroll
        for (int k = 0; k < 4; ++k) {
            int sp = sp_g + 16*k;
            int oy = sp >> 3, ox = sp & 7;
            out[((co*DO + bz)*HO + oy0+oy)*WO + ox0+ox] = acc[j][k];
        }
    }
}

// ---------------- per-channel BN stats for channel-major tensors ---------
template<int SPL>
__global__ void bn_stats_cmajor(const float* __restrict__ y, const float* __restrict__ g,
                                const float* __restrict__ be, float* __restrict__ ss, int C) {
    __shared__ float s_red[2][256];
    int c = blockIdx.x;
    const float* p = y + (size_t)c*SPL;
    float sum = 0.f, sq = 0.f;
    for (int i = threadIdx.x; i < SPL; i += 256) { float v = p[i]; sum += v; sq += v*v; }
    s_red[0][threadIdx.x] = sum; s_red[1][threadIdx.x] = sq;
    __syncthreads();
    for (int s = 128; s > 0; s >>= 1) {
        if (threadIdx.x < s) {
            s_red[0][threadIdx.x] += s_red[0][threadIdx.x+s];
            s_red[1][threadIdx.x] += s_red[1][threadIdx.x+s];
        }
        __syncthreads();
    }
    if (threadIdx.x == 0) {
        float invN = 1.f/(float)SPL;
        float mean = s_red[0][0]*invN;
        float var  = s_red[1][0]*invN - mean*mean;
        float sc = g[c]*rsqrtf(var + EPSBN);
        ss[c] = sc; ss[C+c] = be[c] - mean*sc;
    }
}

template<int LOGSPL>
__global__ void bn_apply_cmajor(float* __restrict__ y, const float* __restrict__ ss,
                                int C, int total) {
    for (int i = blockIdx.x*blockDim.x + threadIdx.x; i < total; i += gridDim.x*blockDim.x) {
        int c = i >> LOGSPL;
        y[i] = fmaxf(0.f, y[i]*ss[c] + ss[C+c]);
    }
}

// ---------------- host launcher ------------------------------------------
extern "C" void kernel_launch(void* const* d_in, const int* in_sizes, int n_in,
                              void* d_out, int out_size, void* d_ws, size_t ws_size,
                              hipStream_t stream) {
    const float* x      = (const float*)d_in[0];   // (1,12000,32,5)
    const int*   coords = (const int*)  d_in[1];   // (1,12000,3)
    // d_in[2..4] = grid dims (16,128,128) — hardcoded above
    const float* w1  = (const float*)d_in[5];
    const float* g1  = (const float*)d_in[7];
    const float* be1 = (const float*)d_in[8];
    const float* w2  = (const float*)d_in[9];
    const float* g2  = (const float*)d_in[11];
    const float* be2 = (const float*)d_in[12];
    const float* cw1 = (const float*)d_in[13];
    const float* cg1 = (const float*)d_in[15];
    const float* cbe1= (const float*)d_in[16];
    const float* cw2 = (const float*)d_in[17];
    const float* cg2 = (const float*)d_in[19];
    const float* cbe2= (const float*)d_in[20];
    const float* cw3 = (const float*)d_in[21];
    const float* cg3 = (const float*)d_in[23];
    const float* cbe3= (const float*)d_in[24];
    float* out = (float*)d_out;

    // ---- workspace layout (floats) ----
    // [stats 2048][grid 33,554,432][poolA: max(f1+f2+winner, c1o+c2o) = 5,242,880]
    float* ws    = (float*)d_ws;
    float* stats = ws;                         // 2048 floats
    float* grid  = ws + 2048;                  // C2*SP
    float* poolA = grid + (size_t)C2*SP;
    float* f1    = poolA;                      // 12000*64
    float* y2    = f1 + NVOX*C1;               // 12000*128
    int*   winner= (int*)(y2 + NVOX*C2);       // SP ints
    float* c1o   = poolA;                      // 128*8*64*64 = 4,194,304 (reuses f1/y2/winner)
    float* c2o   = poolA + 4194304;            // 256*4*32*32 = 1,048,576

    float* s1sum = stats;        // 128
    float* ss1   = stats + 128;  // 128
    float* s2sum = stats + 256;  // 256
    float* ss2   = stats + 512;  // 256
    float* ssc1  = stats + 768;  // 256
    float* ssc2  = stats + 1024; // 512
    float* ssc3  = stats + 1536; // 512

    hipMemsetAsync(stats, 0, 2048*sizeof(float), stream);
    hipMemsetAsync(winner, 0xFF, SP*sizeof(int), stream);  // all -1

    // VFE1
    vfe1_stats<<<960, 256, 0, stream>>>(x, w1, s1sum);
    bn_finalize<<<1, 64, 0, stream>>>(s1sum, g1, be1, ss1, C1, 1.f/(NVOX*NPTS));
    vfe1_apply<<<NVOX, 64, 0, stream>>>(x, w1, ss1, f1);
    // VFE2
    vfe2_linear<<<NVOX/16, 128, 0, stream>>>(f1, w2, y2, s2sum);
    bn_finalize<<<1, 128, 0, stream>>>(s2sum, g2, be2, ss2, C2, 1.f/NVOX);
    vfe2_apply<<<(NVOX*C2+255)/256, 256, 0, stream>>>(y2, ss2);
    // scatter to dense grid
    scatter_winner<<<(NVOX+255)/256, 256, 0, stream>>>(coords, winner);
    build_grid<<<4096, 256, 0, stream>>>(winner, y2, grid);
    // conv1: 128 -> 128, (16,128,128) -> (8,64,64)
    conv3d_s2<128,128,16,128,128,8,64,64><<<8*8*8*2, 256, 0, stream>>>(grid, cw1, c1o);
    bn_stats_cmajor<8*64*64><<<128, 256, 0, stream>>>(c1o, cg1, cbe1, ssc1, 128);
    bn_apply_cmajor<15><<<2048, 256, 0, stream>>>(c1o, ssc1, 128, 128*8*64*64);
    // conv2: 128 -> 256, (8,64,64) -> (4,32,32)
    conv3d_s2<128,256,8,64,64,4,32,32><<<4*4*4*4, 256, 0, stream>>>(c1o, cw2, c2o);
    bn_stats_cmajor<4*32*32><<<256, 256, 0, stream>>>(c2o, cg2, cbe2, ssc2, 256);
    bn_apply_cmajor<12><<<1024, 256, 0, stream>>>(c2o, ssc2, 256, 256*4*32*32);
    // conv3: 256 -> 256, (4,32,32) -> (2,16,16), raw into d_out then BN in place
    conv3d_s2<256,256,4,32,32,2,16,16><<<2*2*2*4, 256, 0, stream>>>(c2o, cw3, out);
    bn_stats_cmajor<2*16*16><<<256, 256, 0, stream>>>(out, cg3, cbe3, ssc3, 256);
    bn_apply_cmajor<9><<<512, 256, 0, stream>>>(out, ssc3, 256, 256*2*16*16);
}

// Round 2
// 447.916 us; speedup vs baseline: 5.7931x; 5.7931x over previous
//
#include <hip/hip_runtime.h>

// ---------------- problem constants (match reference setup_inputs) ----------
#define NVOX 12000
#define NPTS 32
#define CIN  5
#define C1   64     // VFE1 out
#define C2   128    // VFE2 out
#define GD   16
#define GH   128
#define GW   128
#define SP   (GD*GH*GW)          // 262144 = 2^18
static constexpr float EPSBN = 1e-5f;

typedef unsigned short ushortT;
typedef __attribute__((ext_vector_type(8))) short bf16x8;
typedef __attribute__((ext_vector_type(4))) short bf16x4;
typedef __attribute__((ext_vector_type(4))) float f32x4;

__device__ inline ushortT f2bf(float f) {
    unsigned int x = __float_as_uint(f);
    unsigned int r = (x + 0x7FFFu + ((x >> 16) & 1u)) >> 16;   // RNE
    return (ushortT)r;
}
__device__ inline float bf2f(ushortT u) { return __uint_as_float(((unsigned int)u) << 16); }

__device__ inline bf16x8 ld_frag(const ushortT* p) {
    bf16x8 r;
    ((bf16x4*)&r)[0] = *(const bf16x4*)p;
    ((bf16x4*)&r)[1] = *(const bf16x4*)(p + 4);
    return r;
}

// NOTE: biases (b1,b2,cb1..3) are mathematically no-ops: every linear/conv is
// immediately followed by training-mode BN which subtracts the per-channel
// mean; a per-channel constant shifts mean but not variance. Skipped.

// ---------------- VFE1 stats ------------------------------------------------
__global__ void vfe1_stats(const float* __restrict__ x, const float* __restrict__ w1,
                           float* __restrict__ sums) {
    __shared__ float s_w[CIN*C1];
    __shared__ float s_red[2][4][C1];
    int t = threadIdx.x; // 256
    for (int i = t; i < CIN*C1; i += 256) s_w[i] = w1[i];
    __syncthreads();
    int ch = t & 63, rr = t >> 6;
    float sum = 0.f, sq = 0.f;
    const int NROWS = NVOX * NPTS;
    for (int row = blockIdx.x*4 + rr; row < NROWS; row += gridDim.x*4) {
        const float* xr = x + row*CIN;
        float y = 0.f;
        #pragma unroll
        for (int c = 0; c < CIN; ++c) y += xr[c] * s_w[c*C1 + ch];
        sum += y; sq += y*y;
    }
    s_red[0][rr][ch] = sum; s_red[1][rr][ch] = sq;
    __syncthreads();
    if (rr == 0) {
        sum = s_red[0][0][ch]+s_red[0][1][ch]+s_red[0][2][ch]+s_red[0][3][ch];
        sq  = s_red[1][0][ch]+s_red[1][1][ch]+s_red[1][2][ch]+s_red[1][3][ch];
        atomicAdd(&sums[ch], sum);
        atomicAdd(&sums[C1+ch], sq);
    }
}

__global__ void bn_finalize(const float* __restrict__ sums, const float* __restrict__ g,
                            const float* __restrict__ be, float* __restrict__ ss,
                            int C, float invN) {
    int c = blockIdx.x*blockDim.x + threadIdx.x;
    if (c >= C) return;
    float mean = sums[c]*invN;
    float var  = sums[C+c]*invN - mean*mean;
    float sc = g[c]*rsqrtf(var + EPSBN);
    ss[c] = sc; ss[C+c] = be[c] - mean*sc;
}

__global__ void vfe1_apply(const float* __restrict__ x, const float* __restrict__ w1,
                           const float* __restrict__ ss, float* __restrict__ f1) {
    __shared__ float s_w[CIN*C1];
    __shared__ float s_x[NPTS*CIN];
    int v = blockIdx.x, t = threadIdx.x; // 64 threads
    for (int i = t; i < CIN*C1; i += 64) s_w[i] = w1[i];
    for (int i = t; i < NPTS*CIN; i += 64) s_x[i] = x[v*NPTS*CIN + i];
    __syncthreads();
    float sc = ss[t], sh = ss[C1+t];
    float m = 0.f;
    for (int p = 0; p < NPTS; ++p) {
        float y = 0.f;
        #pragma unroll
        for (int c = 0; c < CIN; ++c) y += s_x[p*CIN+c]*s_w[c*C1+t];
        m = fmaxf(m, y*sc + sh);
    }
    f1[v*C1 + t] = m;
}

__global__ void vfe2_linear(const float* __restrict__ f1, const float* __restrict__ w2,
                            float* __restrict__ y2, float* __restrict__ sums) {
    __shared__ float s_w[C1*C2];
    __shared__ float s_f[16*C1];
    int t = threadIdx.x; // 128
    for (int i = t; i < C1*C2; i += 128) s_w[i] = w2[i];
    int v0 = blockIdx.x*16;
    for (int i = t; i < 16*C1; i += 128) s_f[i] = f1[v0*C1 + i];
    __syncthreads();
    float sum = 0.f, sq = 0.f;
    for (int vl = 0; vl < 16; ++vl) {
        float y = 0.f;
        #pragma unroll 8
        for (int c = 0; c < C1; ++c) y += s_f[vl*C1+c]*s_w[c*C2+t];
        y2[(v0+vl)*C2 + t] = y;
        sum += y; sq += y*y;
    }
    atomicAdd(&sums[t], sum);
    atomicAdd(&sums[C2+t], sq);
}

__global__ void vfe2_apply_bf16(const float* __restrict__ y2, const float* __restrict__ ss,
                                ushortT* __restrict__ f2b) {
    int i = blockIdx.x*blockDim.x + threadIdx.x;
    if (i >= NVOX*C2) return;
    int c = i & (C2-1);
    f2b[i] = f2bf(fmaxf(0.f, y2[i]*ss[c] + ss[C2+c]));
}

// ---------------- scatter (last-write-wins via max voxel index) ------------
__global__ void scatter_winner(const int* __restrict__ coords, int* __restrict__ winner) {
    int v = blockIdx.x*blockDim.x + threadIdx.x;
    if (v >= NVOX) return;
    int d = coords[v*3+0], h = coords[v*3+1], w = coords[v*3+2];
    atomicMax(&winner[(d*GH + h)*GW + w], v);
}

// densify, channels-last bf16: grid_cl[sp][128]
__global__ void build_grid_cl(const int* __restrict__ winner, const ushortT* __restrict__ f2b,
                              ushortT* __restrict__ grid_cl) {
    const int total = SP*16; // 16 chunks of 8 ci per spatial cell
    for (int e = blockIdx.x*blockDim.x + threadIdx.x; e < total; e += gridDim.x*blockDim.x) {
        int sp = e >> 4, ch = e & 15;
        int wn = winner[sp];
        int4 v = {0,0,0,0};
        if (wn >= 0) v = *(const int4*)(f2b + (size_t)wn*C2 + ch*8);
        *(int4*)(grid_cl + (size_t)sp*C2 + ch*8) = v;
    }
}

// ---------------- weight conversion: cw[co][ci][27] f32 -> wb[co][cig][tap][32] bf16
__global__ void convert_w(const float* __restrict__ cw, ushortT* __restrict__ wb,
                          int CI_, int total) {
    int ncig = CI_ >> 5;
    for (int e = blockIdx.x*blockDim.x + threadIdx.x; e < total; e += gridDim.x*blockDim.x) {
        int cil = e & 31;
        int r = e >> 5;
        int tap = r % 27; r /= 27;
        int cig = r % ncig;
        int co  = r / ncig;
        wb[e] = f2bf(cw[(size_t)(co*CI_ + cig*32 + cil)*27 + tap]);
    }
}

// ---------------- MFMA implicit-GEMM conv3d, stride 2, pad 1, k=3 ----------
// block: 256 thr = 4 waves (2 co-halves x 2 sp-halves). Block tile: CO_T x 64 sp.
// K = (CI/32 groups) x 27 taps, K-step = 32 (one 16x16x32 MFMA per frag pair).
template<int CI, int CO, int CO_T, int DI, int HI, int WI, int DO, int HO, int WO, bool CMAJOR>
__global__ __launch_bounds__(256) void conv3d_mfma(const ushortT* __restrict__ in_cl,
                                                   const ushortT* __restrict__ wb,
                                                   void* __restrict__ outp) {
    constexpr int NCIG   = CI / 32;
    constexpr int FRAG_M = CO_T / 32;          // co frags per wave (wave tile M = CO_T/2)
    constexpr int WCH    = CO_T * 4 / 256;     // weight 16B-chunks per thread
    __shared__ ushortT s_in[867*36];           // 3*17*17 positions x (32 ci + 4 pad)
    __shared__ ushortT s_w[2*CO_T*36];         // double-buffered per-tap weight tile

    const int nbx = WO/8, nby = HO/8;
    int b = blockIdx.x;
    int bx = b % nbx; b /= nbx;
    int by = b % nby; b /= nby;
    int bz = b % DO;  b /= DO;
    const int co0 = b * CO_T;
    const int oy0 = by*8, ox0 = bx*8;
    const int t = threadIdx.x;
    const int lane = t & 63, wid = t >> 6;
    const int lr = lane & 15, lq = lane >> 4;
    const int wm = wid & 1, wn = wid >> 1;

    f32x4 acc[FRAG_M][2];
    #pragma unroll
    for (int i = 0; i < FRAG_M; ++i)
        #pragma unroll
        for (int j = 0; j < 2; ++j) acc[i][j] = (f32x4){0.f,0.f,0.f,0.f};

    for (int cig = 0; cig < NCIG; ++cig) {
        // ---- stage input halo tile (3x17x17 x 32ci), zero-padded ----
        for (int c = t; c < 867*4; c += 256) {
            int pos = c >> 2, sub = c & 3;
            int zz = pos / 289; int rr = pos - zz*289;
            int yy = rr / 17;   int xx = rr - yy*17;
            int iz = 2*bz  - 1 + zz;
            int iy = 2*oy0 - 1 + yy;
            int ix = 2*ox0 - 1 + xx;
            int4 v = {0,0,0,0};
            if ((unsigned)iz < (unsigned)DI && (unsigned)iy < (unsigned)HI &&
                (unsigned)ix < (unsigned)WI)
                v = *(const int4*)(in_cl + (size_t)((iz*HI + iy)*WI + ix)*CI + cig*32 + sub*8);
            *(int2*)(s_in + pos*36 + sub*8)     = *(int2*)&v;
            *(int2*)(s_in + pos*36 + sub*8 + 4) = *((int2*)&v + 1);
        }
        // ---- stage weights for tap 0 into buffer 0 ----
        #pragma unroll
        for (int j = 0; j < WCH; ++j) {
            int c = t + j*256;
            int co = c >> 2, sub = c & 3;
            const int4 v = *(const int4*)(wb + ((size_t)(co0+co)*NCIG + cig)*27*32 + sub*8);
            *(int2*)(s_w + co*36 + sub*8)     = *(int2*)&v;
            *(int2*)(s_w + co*36 + sub*8 + 4) = *((int2*)&v + 1);
        }
        __syncthreads();

        for (int tap = 0; tap < 27; ++tap) {
            // issue next-tap weight loads early (hide under MFMA)
            int4 wv[WCH];
            const bool pf = (tap < 26);
            if (pf) {
                #pragma unroll
                for (int j = 0; j < WCH; ++j) {
                    int c = t + j*256;
                    int co = c >> 2, sub = c & 3;
                    wv[j] = *(const int4*)(wb + ((size_t)(co0+co)*NCIG + cig)*27*32
                                              + (tap+1)*32 + sub*8);
                }
            }
            const int kz = tap/9, kr = tap%9, ky = kr/3, kx = kr%3;
            const ushortT* swc = s_w + (tap&1)*CO_T*36;

            bf16x8 bfr[2];
            #pragma unroll
            for (int fn = 0; fn < 2; ++fn) {
                int n = wn*32 + fn*16 + lr;
                int oy = n >> 3, ox = n & 7;
                int pos = (kz*17 + (2*oy+ky))*17 + (2*ox+kx);
                bfr[fn] = ld_frag(s_in + pos*36 + lq*8);
            }
            #pragma unroll
            for (int fm = 0; fm < FRAG_M; ++fm) {
                int co = wm*(CO_T/2) + fm*16 + lr;
                bf16x8 afr = ld_frag(swc + co*36 + lq*8);
                acc[fm][0] = __builtin_amdgcn_mfma_f32_16x16x32_bf16(afr, bfr[0], acc[fm][0], 0,0,0);
                acc[fm][1] = __builtin_amdgcn_mfma_f32_16x16x32_bf16(afr, bfr[1], acc[fm][1], 0,0,0);
            }
            if (pf) {
                ushortT* swn = s_w + ((tap+1)&1)*CO_T*36;
                #pragma unroll
                for (int j = 0; j < WCH; ++j) {
                    int c = t + j*256;
                    int co = c >> 2, sub = c & 3;
                    *(int2*)(swn + co*36 + sub*8)     = *(int2*)&wv[j];
                    *(int2*)(swn + co*36 + sub*8 + 4) = *((int2*)&wv[j] + 1);
                }
            }
            __syncthreads();
        }
    }

    // ---- epilogue: D row = co = 4*lq + reg (+frag), col = sp = lr ----
    if (!CMAJOR) {
        ushortT* out = (ushortT*)outp;
        #pragma unroll
        for (int fm = 0; fm < FRAG_M; ++fm)
        #pragma unroll
        for (int fn = 0; fn < 2; ++fn) {
            int n = wn*32 + fn*16 + lr;
            int oy = n >> 3, ox = n & 7;
            size_t sp = ((size_t)bz*HO + (oy0+oy))*WO + (ox0+ox);
            int cob = co0 + wm*(CO_T/2) + fm*16 + lq*4;
            ushort4 o;
            o.x = f2bf(acc[fm][fn][0]); o.y = f2bf(acc[fm][fn][1]);
            o.z = f2bf(acc[fm][fn][2]); o.w = f2bf(acc[fm][fn][3]);
            *(ushort4*)(out + sp*CO + cob) = o;
        }
    } else {
        float* out = (float*)outp;
        #pragma unroll
        for (int fm = 0; fm < FRAG_M; ++fm)
        #pragma unroll
        for (int fn = 0; fn < 2; ++fn) {
            int n = wn*32 + fn*16 + lr;
            int oy = n >> 3, ox = n & 7;
            int cob = co0 + wm*(CO_T/2) + fm*16 + lq*4;
            #pragma unroll
            for (int r = 0; r < 4; ++r)
                out[((size_t)(cob+r)*DO + bz)*HO*WO + (oy0+oy)*WO + (ox0+ox)] = acc[fm][fn][r];
        }
    }
}

// ---------------- BN for channels-last bf16 tensors ------------------------
template<int C>
__global__ void bn_stats_cl(const ushortT* __restrict__ y, float* __restrict__ sums, int SPL) {
    constexpr int R = 256 / C;
    int t = threadIdx.x;
    int c = t & (C-1);
    int r = t / C;
    float sum = 0.f, sq = 0.f;
    for (int sp = blockIdx.x*R + r; sp < SPL; sp += gridDim.x*R) {
        float v = bf2f(y[(size_t)sp*C + c]);
        sum += v; sq += v*v;
    }
    __shared__ float red[2][256];
    red[0][t] = sum; red[1][t] = sq;
    __syncthreads();
    if (R == 2 && t < C) { sum += red[0][t+C]; sq += red[1][t+C]; }
    if (t < C) { atomicAdd(&sums[c], sum); atomicAdd(&sums[C+c], sq); }
}

template<int C>
__global__ void bn_apply_cl(ushortT* __restrict__ y, const float* __restrict__ ss, int total) {
    for (int i = blockIdx.x*blockDim.x + threadIdx.x; i < total; i += gridDim.x*blockDim.x) {
        int c = i & (C-1);
        y[i] = f2bf(fmaxf(0.f, bf2f(y[i])*ss[c] + ss[C+c]));
    }
}

// ---------------- BN for channel-major fp32 (final output) -----------------
template<int SPL>
__global__ void bn_stats_cmajor(const float* __restrict__ y, const float* __restrict__ g,
                                const float* __restrict__ be, float* __restrict__ ss, int C) {
    __shared__ float s_red[2][256];
    int c = blockIdx.x;
    const float* p = y + (size_t)c*SPL;
    float sum = 0.f, sq = 0.f;
    for (int i = threadIdx.x; i < SPL; i += 256) { float v = p[i]; sum += v; sq += v*v; }
    s_red[0][threadIdx.x] = sum; s_red[1][threadIdx.x] = sq;
    __syncthreads();
    for (int s = 128; s > 0; s >>= 1) {
        if (threadIdx.x < s) {
            s_red[0][threadIdx.x] += s_red[0][threadIdx.x+s];
            s_red[1][threadIdx.x] += s_red[1][threadIdx.x+s];
        }
        __syncthreads();
    }
    if (threadIdx.x == 0) {
        float invN = 1.f/(float)SPL;
        float mean = s_red[0][0]*invN;
        float var  = s_red[1][0]*invN - mean*mean;
        float sc = g[c]*rsqrtf(var + EPSBN);
        ss[c] = sc; ss[C+c] = be[c] - mean*sc;
    }
}

template<int LOGSPL>
__global__ void bn_apply_cmajor(float* __restrict__ y, const float* __restrict__ ss,
                                int C, int total) {
    for (int i = blockIdx.x*blockDim.x + threadIdx.x; i < total; i += gridDim.x*blockDim.x) {
        int c = i >> LOGSPL;
        y[i] = fmaxf(0.f, y[i]*ss[c] + ss[C+c]);
    }
}

// ---------------- host launcher --------------------------------------------
extern "C" void kernel_launch(void* const* d_in, const int* in_sizes, int n_in,
                              void* d_out, int out_size, void* d_ws, size_t ws_size,
                              hipStream_t stream) {
    const float* x      = (const float*)d_in[0];
    const int*   coords = (const int*)  d_in[1];
    const float* w1  = (const float*)d_in[5];
    const float* g1  = (const float*)d_in[7];
    const float* be1 = (const float*)d_in[8];
    const float* w2  = (const float*)d_in[9];
    const float* g2  = (const float*)d_in[11];
    const float* be2 = (const float*)d_in[12];
    const float* cw1 = (const float*)d_in[13];
    const float* cg1 = (const float*)d_in[15];
    const float* cbe1= (const float*)d_in[16];
    const float* cw2 = (const float*)d_in[17];
    const float* cg2 = (const float*)d_in[19];
    const float* cbe2= (const float*)d_in[20];
    const float* cw3 = (const float*)d_in[21];
    const float* cg3 = (const float*)d_in[23];
    const float* cbe3= (const float*)d_in[24];
    float* out = (float*)d_out;

    // ---- workspace layout ----
    float*  ws      = (float*)d_ws;
    float*  stats   = ws;                                   // 4096 f32
    ushortT* grid_cl = (ushortT*)(ws + 4096);               // SP*128
    float*  f1      = (float*)(grid_cl + (size_t)SP*C2);    // 12000*64
    float*  y2      = f1 + NVOX*C1;                         // 12000*128
    ushortT* f2b    = (ushortT*)(y2 + NVOX*C2);             // 12000*128
    int*    winner  = (int*)(f2b + NVOX*C2);                // SP
    ushortT* c1o    = (ushortT*)(winner + SP);              // 32768*128
    ushortT* c2o    = c1o + (size_t)32768*128;              // 4096*256
    ushortT* wb1    = c2o + (size_t)4096*256;               // 128*4*27*32
    ushortT* wb2    = wb1 + 442368;                         // 256*4*27*32
    ushortT* wb3    = wb2 + 884736;                         // 256*8*27*32

    float* s1sum = stats;        // 128
    float* ss1   = stats + 128;  // 128
    float* s2sum = stats + 256;  // 256
    float* ss2   = stats + 512;  // 256
    float* c1sum = stats + 768;  // 256
    float* ssc1  = stats + 1024; // 256
    float* c2sum = stats + 1280; // 512
    float* ssc2  = stats + 1792; // 512
    float* ssc3  = stats + 2304; // 512

    hipMemsetAsync(stats, 0, 4096*sizeof(float), stream);
    hipMemsetAsync(winner, 0xFF, SP*sizeof(int), stream);

    // weight conversions (independent)
    convert_w<<<512, 256, 0, stream>>>(cw1, wb1, 128, 442368);
    convert_w<<<512, 256, 0, stream>>>(cw2, wb2, 128, 884736);
    convert_w<<<512, 256, 0, stream>>>(cw3, wb3, 256, 1769472);

    // VFE1
    vfe1_stats<<<960, 256, 0, stream>>>(x, w1, s1sum);
    bn_finalize<<<1, 64, 0, stream>>>(s1sum, g1, be1, ss1, C1, 1.f/(NVOX*NPTS));
    vfe1_apply<<<NVOX, 64, 0, stream>>>(x, w1, ss1, f1);
    // VFE2
    vfe2_linear<<<NVOX/16, 128, 0, stream>>>(f1, w2, y2, s2sum);
    bn_finalize<<<1, 128, 0, stream>>>(s2sum, g2, be2, ss2, C2, 1.f/NVOX);
    vfe2_apply_bf16<<<(NVOX*C2+255)/256, 256, 0, stream>>>(y2, ss2, f2b);
    // scatter + densify (channels-last bf16)
    scatter_winner<<<(NVOX+255)/256, 256, 0, stream>>>(coords, winner);
    build_grid_cl<<<2048, 256, 0, stream>>>(winner, f2b, grid_cl);

    // conv1: 128->128, (16,128,128)->(8,64,64)
    conv3d_mfma<128,128,128, 16,128,128, 8,64,64, false>
        <<<8*8*8, 256, 0, stream>>>(grid_cl, wb1, c1o);
    bn_stats_cl<128><<<256, 256, 0, stream>>>(c1o, c1sum, 32768);
    bn_finalize<<<1, 128, 0, stream>>>(c1sum, cg1, cbe1, ssc1, 128, 1.f/32768.f);
    bn_apply_cl<128><<<2048, 256, 0, stream>>>(c1o, ssc1, 32768*128);

    // conv2: 128->256, (8,64,64)->(4,32,32)
    conv3d_mfma<128,256,128, 8,64,64, 4,32,32, false>
        <<<4*4*4*2, 256, 0, stream>>>(c1o, wb2, c2o);
    bn_stats_cl<256><<<64, 256, 0, stream>>>(c2o, c2sum, 4096);
    bn_finalize<<<1, 256, 0, stream>>>(c2sum, cg2, cbe2, ssc2, 256, 1.f/4096.f);
    bn_apply_cl<256><<<1024, 256, 0, stream>>>(c2o, ssc2, 4096*256);

    // conv3: 256->256, (4,32,32)->(2,16,16), fp32 channel-major into d_out
    conv3d_mfma<256,256,128, 4,32,32, 2,16,16, true>
        <<<2*2*2*2, 256, 0, stream>>>(c2o, wb3, (void*)out);
    bn_stats_cmajor<2*16*16><<<256, 256, 0, stream>>>(out, cg3, cbe3, ssc3, 256);
    bn_apply_cmajor<9><<<512, 256, 0, stream>>>(out, ssc3, 256, 131072);
}

// Round 3
// 387.284 us; speedup vs baseline: 6.7000x; 1.1566x over previous
//
#include <hip/hip_runtime.h>

// ---------------- problem constants (match reference setup_inputs) ----------
#define NVOX 12000
#define NPTS 32
#define CIN  5
#define C1   64     // VFE1 out
#define C2   128    // VFE2 out
#define GD   16
#define GH   128
#define GW   128
#define SP   (GD*GH*GW)          // 262144
static constexpr float EPSBN = 1e-5f;

typedef unsigned short ushortT;
typedef __attribute__((ext_vector_type(8))) short bf16x8;
typedef __attribute__((ext_vector_type(4))) float f32x4;

__device__ inline ushortT f2bf(float f) {
    unsigned int x = __float_as_uint(f);
    unsigned int r = (x + 0x7FFFu + ((x >> 16) & 1u)) >> 16;   // RNE
    return (ushortT)r;
}
__device__ inline float bf2f(ushortT u) { return __uint_as_float(((unsigned int)u) << 16); }

// NOTE: biases (b1,b2,cb1..3) are mathematically no-ops: every linear/conv is
// immediately followed by training-mode BN which subtracts the per-channel
// mean; a per-channel constant shifts mean but not variance. Skipped.

// ---------------- VFE1 stats ------------------------------------------------
__global__ void vfe1_stats(const float* __restrict__ x, const float* __restrict__ w1,
                           float* __restrict__ sums) {
    __shared__ float s_w[CIN*C1];
    __shared__ float s_red[2][4][C1];
    int t = threadIdx.x; // 256
    for (int i = t; i < CIN*C1; i += 256) s_w[i] = w1[i];
    __syncthreads();
    int ch = t & 63, rr = t >> 6;
    float sum = 0.f, sq = 0.f;
    const int NROWS = NVOX * NPTS;
    for (int row = blockIdx.x*4 + rr; row < NROWS; row += gridDim.x*4) {
        const float* xr = x + row*CIN;
        float y = 0.f;
        #pragma unroll
        for (int c = 0; c < CIN; ++c) y += xr[c] * s_w[c*C1 + ch];
        sum += y; sq += y*y;
    }
    s_red[0][rr][ch] = sum; s_red[1][rr][ch] = sq;
    __syncthreads();
    if (rr == 0) {
        sum = s_red[0][0][ch]+s_red[0][1][ch]+s_red[0][2][ch]+s_red[0][3][ch];
        sq  = s_red[1][0][ch]+s_red[1][1][ch]+s_red[1][2][ch]+s_red[1][3][ch];
        atomicAdd(&sums[ch], sum);
        atomicAdd(&sums[C1+ch], sq);
    }
}

// VFE1 apply: inline BN finalize (thread t == channel t)
__global__ void vfe1_apply(const float* __restrict__ x, const float* __restrict__ w1,
                           const float* __restrict__ sums, const float* __restrict__ g,
                           const float* __restrict__ be, float* __restrict__ f1) {
    __shared__ float s_w[CIN*C1];
    __shared__ float s_x[NPTS*CIN];
    int v = blockIdx.x, t = threadIdx.x; // 64 threads
    for (int i = t; i < CIN*C1; i += 64) s_w[i] = w1[i];
    for (int i = t; i < NPTS*CIN; i += 64) s_x[i] = x[v*NPTS*CIN + i];
    const float invN = 1.f/(NVOX*NPTS);
    float mean = sums[t]*invN;
    float var  = sums[C1+t]*invN - mean*mean;
    float sc = g[t]*rsqrtf(var + EPSBN);
    float sh = be[t] - mean*sc;
    __syncthreads();
    float m = 0.f;
    for (int p = 0; p < NPTS; ++p) {
        float y = 0.f;
        #pragma unroll
        for (int c = 0; c < CIN; ++c) y += s_x[p*CIN+c]*s_w[c*C1+t];
        m = fmaxf(m, y*sc + sh);
    }
    f1[v*C1 + t] = m;
}

__global__ void vfe2_linear(const float* __restrict__ f1, const float* __restrict__ w2,
                            float* __restrict__ y2, float* __restrict__ sums) {
    __shared__ float s_w[C1*C2];
    __shared__ float s_f[16*C1];
    int t = threadIdx.x; // 128
    for (int i = t; i < C1*C2; i += 128) s_w[i] = w2[i];
    int v0 = blockIdx.x*16;
    for (int i = t; i < 16*C1; i += 128) s_f[i] = f1[v0*C1 + i];
    __syncthreads();
    float sum = 0.f, sq = 0.f;
    for (int vl = 0; vl < 16; ++vl) {
        float y = 0.f;
        #pragma unroll 8
        for (int c = 0; c < C1; ++c) y += s_f[vl*C1+c]*s_w[c*C2+t];
        y2[(v0+vl)*C2 + t] = y;
        sum += y; sq += y*y;
    }
    atomicAdd(&sums[t], sum);
    atomicAdd(&sums[C2+t], sq);
}

// VFE2 apply -> bf16, inline finalize, 4 elems/thread
__global__ void vfe2_apply_bf16(const float* __restrict__ y2, const float* __restrict__ sums,
                                const float* __restrict__ g, const float* __restrict__ be,
                                ushortT* __restrict__ f2b) {
    __shared__ float s_sc[C2], s_sh[C2];
    int t = threadIdx.x;
    if (t < C2) {
        const float invN = 1.f/NVOX;
        float mean = sums[t]*invN;
        float var  = sums[C2+t]*invN - mean*mean;
        float sc = g[t]*rsqrtf(var + EPSBN);
        s_sc[t] = sc; s_sh[t] = be[t] - mean*sc;
    }
    __syncthreads();
    int i = blockIdx.x*256 + t;
    if (i >= NVOX*C2/4) return;
    const float4 v = *(const float4*)(y2 + (size_t)i*4);
    int c0 = (i*4) & (C2-1);
    ushort4 o;
    o.x = f2bf(fmaxf(0.f, v.x*s_sc[c0+0]+s_sh[c0+0]));
    o.y = f2bf(fmaxf(0.f, v.y*s_sc[c0+1]+s_sh[c0+1]));
    o.z = f2bf(fmaxf(0.f, v.z*s_sc[c0+2]+s_sh[c0+2]));
    o.w = f2bf(fmaxf(0.f, v.w*s_sc[c0+3]+s_sh[c0+3]));
    *(ushort4*)(f2b + (size_t)i*4) = o;
}

// ---------------- scatter (last-write-wins via max voxel index) ------------
__global__ void scatter_winner(const int* __restrict__ coords, int* __restrict__ winner) {
    int v = blockIdx.x*blockDim.x + threadIdx.x;
    if (v >= NVOX) return;
    int d = coords[v*3+0], h = coords[v*3+1], w = coords[v*3+2];
    atomicMax(&winner[(d*GH + h)*GW + w], v);
}

// ---------------- weight conversion: all three sets, A-fragment tile layout -
// wb[cig][tap][cog][lane][8]: lane holds A[row=lane&15][k=(lane>>4)*8+j]
__global__ void convert_w3(const float* __restrict__ cw1, const float* __restrict__ cw2,
                           const float* __restrict__ cw3, ushortT* __restrict__ wb1,
                           ushortT* __restrict__ wb2, ushortT* __restrict__ wb3) {
    const int N1 = 4*27*8*512;     // 442368
    const int N2 = 4*27*16*512;    // 884736
    const int N3 = 8*27*16*512;    // 1769472
    const int total = N1+N2+N3;
    for (int e0 = blockIdx.x*blockDim.x + threadIdx.x; e0 < total; e0 += gridDim.x*blockDim.x) {
        const float* cw; ushortT* wb; int CI_, NCOG_, e;
        if (e0 < N1)            { cw=cw1; wb=wb1; CI_=128; NCOG_=8;  e=e0; }
        else if (e0 < N1+N2)    { cw=cw2; wb=wb2; CI_=128; NCOG_=16; e=e0-N1; }
        else                    { cw=cw3; wb=wb3; CI_=256; NCOG_=16; e=e0-N1-N2; }
        int j = e & 7, lane = (e>>3) & 63, r = e >> 9;
        int cog = r % NCOG_; r /= NCOG_;
        int tap = r % 27;    int cig = r / 27;
        int co = cog*16 + (lane & 15);
        int ci = cig*32 + (lane>>4)*8 + j;
        wb[e] = f2bf(cw[((size_t)co*CI_ + ci)*27 + tap]);
    }
}

// ---------------- MFMA implicit-GEMM conv3d, stride 2, pad 1, k=3 ----------
// 256 thr = 4 waves (2 co x 2 sp). Block tile CO_T x 64 sp. Barrier-free tap
// loop: A-frags direct from global (L2), B-frags ds_read_b128 w/ imm offsets.
// MODE 0: gather via winner + bf16 out + fused stats (conv1)
// MODE 1: dense bf16 in + bf16 out + fused stats (conv2)
// MODE 2: dense bf16 in + split-K fp32 atomic out (conv3)
template<int CI, int CO, int CO_T, int DI, int HI, int WI, int DO, int HO, int WO,
         int NSLICE, int MODE>
__global__ __launch_bounds__(256, 2) void conv3d_mfma(
        const ushortT* __restrict__ in_cl, const int* __restrict__ winner,
        const ushortT* __restrict__ wb, void* __restrict__ outp,
        float* __restrict__ sums) {
    constexpr int NCIG   = CI/32;
    constexpr int NCOG   = CO/16;
    constexpr int FRAG_M = CO_T/32;
    constexpr int CPB    = NCIG/NSLICE;
    __shared__ ushortT s_in[867*40];   // 3*17*17 positions x (32 ci, stride 40)

    constexpr int nbx = WO/8, nby = HO/8;
    int b = blockIdx.x;
    const int bx = b % nbx; b /= nbx;
    const int by = b % nby; b /= nby;
    const int bz = b % DO;  b /= DO;
    const int cob   = b % (CO/CO_T);
    const int slice = b / (CO/CO_T);
    const int co0 = cob*CO_T;
    const int oy0 = by*8, ox0 = bx*8;
    const int t = threadIdx.x;
    const int lane = t & 63, wid = t >> 6;
    const int lr = lane & 15, lq = lane >> 4;
    const int wm = wid & 1, wn = wid >> 1;
    const int cog0 = (co0 + wm*(CO_T/2)) >> 4;

    int bbase[2];
    #pragma unroll
    for (int fn = 0; fn < 2; ++fn) {
        int n = wn*32 + fn*16 + lr;
        int oy = n >> 3, ox = n & 7;
        bbase[fn] = ((2*oy)*17 + 2*ox)*40 + lq*8;
    }

    f32x4 acc[FRAG_M][2];
    #pragma unroll
    for (int i = 0; i < FRAG_M; ++i)
        #pragma unroll
        for (int j = 0; j < 2; ++j) acc[i][j] = (f32x4){0.f,0.f,0.f,0.f};

    for (int cig = slice*CPB; cig < slice*CPB + CPB; ++cig) {
        __syncthreads();
        for (int c = t; c < 867*4; c += 256) {
            int pos = c >> 2, sub = c & 3;
            int zz = pos/289; int rr = pos - zz*289;
            int yy = rr/17;   int xx = rr - yy*17;
            int iz = 2*bz-1+zz, iy = 2*oy0-1+yy, ix = 2*ox0-1+xx;
            int4 v = {0,0,0,0};
            if ((unsigned)iz < (unsigned)DI && (unsigned)iy < (unsigned)HI &&
                (unsigned)ix < (unsigned)WI) {
                if constexpr (MODE == 0) {
                    int w_ = winner[(iz*HI + iy)*WI + ix];
                    if (w_ >= 0)
                        v = *(const int4*)(in_cl + (size_t)w_*CI + cig*32 + sub*8);
                } else {
                    v = *(const int4*)(in_cl + ((size_t)(iz*HI + iy)*WI + ix)*CI + cig*32 + sub*8);
                }
            }
            *(int4*)(s_in + pos*40 + sub*8) = v;
        }
        __syncthreads();
        const ushortT* wcig = wb + (((size_t)cig*27*NCOG) << 9) + ((size_t)lane << 3);
        #pragma unroll
        for (int tap = 0; tap < 27; ++tap) {
            const int kz = tap/9, ky = (tap/3)%3, kx = tap%3;
            const int toff = (kz*289 + ky*17 + kx)*40;
            bf16x8 bfr0 = *(const bf16x8*)(s_in + bbase[0] + toff);
            bf16x8 bfr1 = *(const bf16x8*)(s_in + bbase[1] + toff);
            #pragma unroll
            for (int fm = 0; fm < FRAG_M; ++fm) {
                bf16x8 afr = *(const bf16x8*)(wcig + (((size_t)(tap*NCOG + cog0 + fm)) << 9));
                acc[fm][0] = __builtin_amdgcn_mfma_f32_16x16x32_bf16(afr, bfr0, acc[fm][0], 0,0,0);
                acc[fm][1] = __builtin_amdgcn_mfma_f32_16x16x32_bf16(afr, bfr1, acc[fm][1], 0,0,0);
            }
        }
    }

    if constexpr (MODE <= 1) {
        ushortT* out = (ushortT*)outp;
        #pragma unroll
        for (int fm = 0; fm < FRAG_M; ++fm)
        #pragma unroll
        for (int fn = 0; fn < 2; ++fn) {
            int n = wn*32 + fn*16 + lr;
            int oy = n >> 3, ox = n & 7;
            size_t sp = ((size_t)bz*HO + oy0+oy)*WO + ox0+ox;
            int c_ = co0 + wm*(CO_T/2) + fm*16 + lq*4;
            ushort4 o;
            o.x = f2bf(acc[fm][fn][0]); o.y = f2bf(acc[fm][fn][1]);
            o.z = f2bf(acc[fm][fn][2]); o.w = f2bf(acc[fm][fn][3]);
            *(ushort4*)(out + sp*CO + c_) = o;
        }
        // fused BN stats (on fp32 accumulators)
        #pragma unroll
        for (int fm = 0; fm < FRAG_M; ++fm) {
            float s[4], q[4];
            #pragma unroll
            for (int r = 0; r < 4; ++r) {
                float a0 = acc[fm][0][r], a1 = acc[fm][1][r];
                s[r] = a0 + a1; q[r] = a0*a0 + a1*a1;
                #pragma unroll
                for (int m = 1; m < 16; m <<= 1) {
                    s[r] += __shfl_xor(s[r], m, 64);
                    q[r] += __shfl_xor(q[r], m, 64);
                }
            }
            if (lr == 0) {
                int c_ = co0 + wm*(CO_T/2) + fm*16 + lq*4;
                #pragma unroll
                for (int r = 0; r < 4; ++r) {
                    atomicAdd(&sums[c_+r], s[r]);
                    atomicAdd(&sums[CO + c_+r], q[r]);
                }
            }
        }
    } else {
        float* out = (float*)outp;
        #pragma unroll
        for (int fm = 0; fm < FRAG_M; ++fm)
        #pragma unroll
        for (int fn = 0; fn < 2; ++fn) {
            int n = wn*32 + fn*16 + lr;
            int oy = n >> 3, ox = n & 7;
            int c_ = co0 + wm*(CO_T/2) + fm*16 + lq*4;
            #pragma unroll
            for (int r = 0; r < 4; ++r)
                atomicAdd(&out[((size_t)(c_+r)*DO + bz)*(HO*WO) + (oy0+oy)*WO + ox0+ox],
                          acc[fm][fn][r]);
        }
    }
}

// ---------------- BN apply, channels-last bf16, inline finalize ------------
template<int C>
__global__ void bn_apply_cl(ushortT* __restrict__ y, const float* __restrict__ sums,
                            const float* __restrict__ g, const float* __restrict__ be,
                            float invN, int total8) {
    __shared__ float s_sc[C], s_sh[C];
    int t = threadIdx.x;
    for (int c = t; c < C; c += 256) {
        float mean = sums[c]*invN;
        float var  = sums[C+c]*invN - mean*mean;
        float sc = g[c]*rsqrtf(var + EPSBN);
        s_sc[c] = sc; s_sh[c] = be[c] - mean*sc;
    }
    __syncthreads();
    for (int i = blockIdx.x*256 + t; i < total8; i += gridDim.x*256) {
        ushortT* p = y + (size_t)i*8;
        int c0 = (i*8) & (C-1);
        ushort4 a = *(ushort4*)p, b4 = *(ushort4*)(p+4);
        ushort4 o1, o2;
        o1.x = f2bf(fmaxf(0.f, bf2f(a.x)*s_sc[c0+0]+s_sh[c0+0]));
        o1.y = f2bf(fmaxf(0.f, bf2f(a.y)*s_sc[c0+1]+s_sh[c0+1]));
        o1.z = f2bf(fmaxf(0.f, bf2f(a.z)*s_sc[c0+2]+s_sh[c0+2]));
        o1.w = f2bf(fmaxf(0.f, bf2f(a.w)*s_sc[c0+3]+s_sh[c0+3]));
        o2.x = f2bf(fmaxf(0.f, bf2f(b4.x)*s_sc[c0+4]+s_sh[c0+4]));
        o2.y = f2bf(fmaxf(0.f, bf2f(b4.y)*s_sc[c0+5]+s_sh[c0+5]));
        o2.z = f2bf(fmaxf(0.f, bf2f(b4.z)*s_sc[c0+6]+s_sh[c0+6]));
        o2.w = f2bf(fmaxf(0.f, bf2f(b4.w)*s_sc[c0+7]+s_sh[c0+7]));
        *(ushort4*)p     = o1;
        *(ushort4*)(p+4) = o2;
    }
}

// ---------------- BN for channel-major fp32 (final output) -----------------
template<int SPL>
__global__ void bn_stats_cmajor(const float* __restrict__ y, const float* __restrict__ g,
                                const float* __restrict__ be, float* __restrict__ ss, int C) {
    __shared__ float s_red[2][256];
    int c = blockIdx.x;
    const float* p = y + (size_t)c*SPL;
    float sum = 0.f, sq = 0.f;
    for (int i = threadIdx.x; i < SPL; i += 256) { float v = p[i]; sum += v; sq += v*v; }
    s_red[0][threadIdx.x] = sum; s_red[1][threadIdx.x] = sq;
    __syncthreads();
    for (int s = 128; s > 0; s >>= 1) {
        if (threadIdx.x < s) {
            s_red[0][threadIdx.x] += s_red[0][threadIdx.x+s];
            s_red[1][threadIdx.x] += s_red[1][threadIdx.x+s];
        }
        __syncthreads();
    }
    if (threadIdx.x == 0) {
        float invN = 1.f/(float)SPL;
        float mean = s_red[0][0]*invN;
        float var  = s_red[1][0]*invN - mean*mean;
        float sc = g[c]*rsqrtf(var + EPSBN);
        ss[c] = sc; ss[C+c] = be[c] - mean*sc;
    }
}

template<int LOGSPL>
__global__ void bn_apply_cmajor(float* __restrict__ y, const float* __restrict__ ss,
                                int C, int total) {
    for (int i = blockIdx.x*blockDim.x + threadIdx.x; i < total; i += gridDim.x*blockDim.x) {
        int c = i >> LOGSPL;
        y[i] = fmaxf(0.f, y[i]*ss[c] + ss[C+c]);
    }
}

// ---------------- host launcher --------------------------------------------
extern "C" void kernel_launch(void* const* d_in, const int* in_sizes, int n_in,
                              void* d_out, int out_size, void* d_ws, size_t ws_size,
                              hipStream_t stream) {
    const float* x      = (const float*)d_in[0];
    const int*   coords = (const int*)  d_in[1];
    const float* w1  = (const float*)d_in[5];
    const float* g1  = (const float*)d_in[7];
    const float* be1 = (const float*)d_in[8];
    const float* w2  = (const float*)d_in[9];
    const float* g2  = (const float*)d_in[11];
    const float* be2 = (const float*)d_in[12];
    const float* cw1 = (const float*)d_in[13];
    const float* cg1 = (const float*)d_in[15];
    const float* cbe1= (const float*)d_in[16];
    const float* cw2 = (const float*)d_in[17];
    const float* cg2 = (const float*)d_in[19];
    const float* cbe2= (const float*)d_in[20];
    const float* cw3 = (const float*)d_in[21];
    const float* cg3 = (const float*)d_in[23];
    const float* cbe3= (const float*)d_in[24];
    float* out = (float*)d_out;

    // ---- workspace layout ----
    float*   ws     = (float*)d_ws;
    float*   stats  = ws;                                   // 4096 f32
    ushortT* f2b    = (ushortT*)(ws + 4096);                // 12000*128
    float*   f1     = (float*)(f2b + (size_t)NVOX*C2);      // 12000*64
    float*   y2     = f1 + (size_t)NVOX*C1;                 // 12000*128
    int*     winner = (int*)(y2 + (size_t)NVOX*C2);         // SP
    ushortT* c1o    = (ushortT*)(winner + SP);              // 32768*128
    ushortT* c2o    = c1o + (size_t)32768*128;              // 4096*256
    ushortT* wb1    = c2o + (size_t)4096*256;               // 442368
    ushortT* wb2    = wb1 + 442368;                         // 884736
    ushortT* wb3    = wb2 + 884736;                         // 1769472

    float* s1sum = stats;          // 128 (64 sum + 64 sq)
    float* s2sum = stats + 128;    // 256
    float* c1sum = stats + 384;    // 256
    float* c2sum = stats + 640;    // 512
    float* ss3   = stats + 1152;   // 512

    hipMemsetAsync(stats, 0, 4096*sizeof(float), stream);
    hipMemsetAsync(winner, 0xFF, SP*sizeof(int), stream);
    hipMemsetAsync(d_out, 0, (size_t)out_size*sizeof(float), stream);

    convert_w3<<<1024, 256, 0, stream>>>(cw1, cw2, cw3, wb1, wb2, wb3);

    // VFE1
    vfe1_stats<<<960, 256, 0, stream>>>(x, w1, s1sum);
    vfe1_apply<<<NVOX, 64, 0, stream>>>(x, w1, s1sum, g1, be1, f1);
    // VFE2
    vfe2_linear<<<NVOX/16, 128, 0, stream>>>(f1, w2, y2, s2sum);
    vfe2_apply_bf16<<<NVOX*C2/4/256, 256, 0, stream>>>(y2, s2sum, g2, be2, f2b);
    // scatter
    scatter_winner<<<(NVOX+255)/256, 256, 0, stream>>>(coords, winner);

    // conv1: 128->128, (16,128,128)->(8,64,64); gathers via winner (no dense grid)
    conv3d_mfma<128,128,128, 16,128,128, 8,64,64, 1, 0>
        <<<8*8*8, 256, 0, stream>>>(f2b, winner, wb1, c1o, c1sum);
    bn_apply_cl<128><<<2048, 256, 0, stream>>>(c1o, c1sum, cg1, cbe1, 1.f/32768.f, 32768*128/8);

    // conv2: 128->256, (8,64,64)->(4,32,32); CO_T=64 -> 256 blocks
    conv3d_mfma<128,256,64, 8,64,64, 4,32,32, 1, 1>
        <<<4*4*4*4, 256, 0, stream>>>(c1o, nullptr, wb2, c2o, c2sum);
    bn_apply_cl<256><<<512, 256, 0, stream>>>(c2o, c2sum, cg2, cbe2, 1.f/4096.f, 4096*256/8);

    // conv3: 256->256, (4,32,32)->(2,16,16); split-K x4, fp32 atomic into d_out
    conv3d_mfma<256,256,64, 4,32,32, 2,16,16, 4, 2>
        <<<2*2*2*4*4, 256, 0, stream>>>(c2o, nullptr, wb3, (void*)out, nullptr);
    bn_stats_cmajor<2*16*16><<<256, 256, 0, stream>>>(out, cg3, cbe3, ss3, 256);
    bn_apply_cmajor<9><<<512, 256, 0, stream>>>(out, ss3, 256, 131072);
}

// Round 4
// 351.680 us; speedup vs baseline: 7.3784x; 1.1012x over previous
//
#include <hip/hip_runtime.h>

// ---------------- problem constants (match reference setup_inputs) ----------
#define NVOX 12000
#define NPTS 32
#define CIN  5
#define C1   64     // VFE1 out
#define C2   128    // VFE2 out
#define GD   16
#define GH   128
#define GW   128
#define SP   (GD*GH*GW)          // 262144
static constexpr float EPSBN = 1e-5f;

typedef unsigned short ushortT;
typedef __attribute__((ext_vector_type(8))) short bf16x8;
typedef __attribute__((ext_vector_type(4))) float f32x4;

__device__ inline ushortT f2bf(float f) {
    unsigned int x = __float_as_uint(f);
    unsigned int r = (x + 0x7FFFu + ((x >> 16) & 1u)) >> 16;   // RNE
    return (ushortT)r;
}
__device__ inline float bf2f(ushortT u) { return __uint_as_float(((unsigned int)u) << 16); }

// NOTE: biases (b1,b2,cb1..3) are mathematically no-ops: every linear/conv is
// immediately followed by training-mode BN which subtracts the per-channel
// mean; a per-channel constant shifts mean but not variance. Skipped.

// ---------------- prep: weight convert + vfe1 stats + scatter (fused) -------
// blocks [0,960): vfe1 stats; [960,1984): weight convert; [1984,2031): scatter
__global__ void prep(const float* __restrict__ x, const float* __restrict__ w1,
                     float* __restrict__ s1sum,
                     const float* __restrict__ cw1, const float* __restrict__ cw2,
                     const float* __restrict__ cw3, ushortT* __restrict__ wb1,
                     ushortT* __restrict__ wb2, ushortT* __restrict__ wb3,
                     const int* __restrict__ coords, int* __restrict__ winner) {
    __shared__ float s_w[CIN*C1];
    __shared__ float s_red[2][4][C1];
    const int blk = blockIdx.x;
    const int t = threadIdx.x;
    if (blk < 960) {
        for (int i = t; i < CIN*C1; i += 256) s_w[i] = w1[i];
        __syncthreads();
        int ch = t & 63, rr = t >> 6;
        float sum = 0.f, sq = 0.f;
        const int NROWS = NVOX * NPTS;
        for (int row = blk*4 + rr; row < NROWS; row += 960*4) {
            const float* xr = x + row*CIN;
            float y = 0.f;
            #pragma unroll
            for (int c = 0; c < CIN; ++c) y += xr[c] * s_w[c*C1 + ch];
            sum += y; sq += y*y;
        }
        s_red[0][rr][ch] = sum; s_red[1][rr][ch] = sq;
        __syncthreads();
        if (rr == 0) {
            sum = s_red[0][0][ch]+s_red[0][1][ch]+s_red[0][2][ch]+s_red[0][3][ch];
            sq  = s_red[1][0][ch]+s_red[1][1][ch]+s_red[1][2][ch]+s_red[1][3][ch];
            atomicAdd(&s1sum[ch], sum);
            atomicAdd(&s1sum[C1+ch], sq);
        }
    } else if (blk < 1984) {
        // wb[e]: e=(((cig*27+tap)*NCOG+cog)*64+lane)*8+j ; A[row=lane&15][k=(lane>>4)*8+j]
        const int N1 = 4*27*8*512, N2 = 4*27*16*512, N3 = 8*27*16*512;
        const int total = N1+N2+N3;
        for (int e0 = (blk-960)*256 + t; e0 < total; e0 += 1024*256) {
            const float* cw; ushortT* wb; int CI_, NCOG_, e;
            if (e0 < N1)         { cw=cw1; wb=wb1; CI_=128; NCOG_=8;  e=e0; }
            else if (e0 < N1+N2) { cw=cw2; wb=wb2; CI_=128; NCOG_=16; e=e0-N1; }
            else                 { cw=cw3; wb=wb3; CI_=256; NCOG_=16; e=e0-N1-N2; }
            int j = e & 7, lane = (e>>3) & 63, r = e >> 9;
            int cog = r % NCOG_; r /= NCOG_;
            int tap = r % 27;    int cig = r / 27;
            int co = cog*16 + (lane & 15);
            int ci = cig*32 + (lane>>4)*8 + j;
            wb[e] = f2bf(cw[((size_t)co*CI_ + ci)*27 + tap]);
        }
    } else {
        int v = (blk-1984)*256 + t;
        if (v < NVOX) {
            int d = coords[v*3+0], h = coords[v*3+1], w = coords[v*3+2];
            atomicMax(&winner[(d*GH + h)*GW + w], v);
        }
    }
}

// ---------------- VFE1 apply: inline BN finalize ---------------------------
__global__ void vfe1_apply(const float* __restrict__ x, const float* __restrict__ w1,
                           const float* __restrict__ sums, const float* __restrict__ g,
                           const float* __restrict__ be, float* __restrict__ f1) {
    __shared__ float s_w[CIN*C1];
    __shared__ float s_x[NPTS*CIN];
    int v = blockIdx.x, t = threadIdx.x; // 64 threads
    for (int i = t; i < CIN*C1; i += 64) s_w[i] = w1[i];
    for (int i = t; i < NPTS*CIN; i += 64) s_x[i] = x[v*NPTS*CIN + i];
    const float invN = 1.f/(NVOX*NPTS);
    float mean = sums[t]*invN;
    float var  = sums[C1+t]*invN - mean*mean;
    float sc = g[t]*rsqrtf(var + EPSBN);
    float sh = be[t] - mean*sc;
    __syncthreads();
    float m = 0.f;
    for (int p = 0; p < NPTS; ++p) {
        float y = 0.f;
        #pragma unroll
        for (int c = 0; c < CIN; ++c) y += s_x[p*CIN+c]*s_w[c*C1+t];
        m = fmaxf(m, y*sc + sh);
    }
    f1[v*C1 + t] = m;
}

// ---------------- VFE2 linear (transposed padded weights, float4 reads) ----
__global__ void vfe2_linear(const float* __restrict__ f1, const float* __restrict__ w2,
                            float* __restrict__ y2, float* __restrict__ sums) {
    __shared__ float s_w[C2][68];   // [out][in], pad to 68 for bank spread
    __shared__ float s_f[16*C1];
    int t = threadIdx.x; // 128
    for (int i = t; i < C1*C2; i += 128) {
        int c = i >> 7, o = i & 127;
        s_w[o][c] = w2[i];
    }
    int v0 = blockIdx.x*16;
    for (int i = t; i < 16*C1; i += 128) s_f[i] = f1[v0*C1 + i];
    __syncthreads();
    float sum = 0.f, sq = 0.f;
    for (int vl = 0; vl < 16; ++vl) {
        float y = 0.f;
        #pragma unroll
        for (int c4 = 0; c4 < C1; c4 += 4) {
            float4 f = *(const float4*)&s_f[vl*C1 + c4];
            float4 w = *(const float4*)&s_w[t][c4];
            y += f.x*w.x + f.y*w.y + f.z*w.z + f.w*w.w;
        }
        y2[(v0+vl)*C2 + t] = y;
        sum += y; sq += y*y;
    }
    atomicAdd(&sums[t], sum);
    atomicAdd(&sums[C2+t], sq);
}

// VFE2 apply -> bf16, inline finalize
__global__ void vfe2_apply_bf16(const float* __restrict__ y2, const float* __restrict__ sums,
                                const float* __restrict__ g, const float* __restrict__ be,
                                ushortT* __restrict__ f2b) {
    __shared__ float s_sc[C2], s_sh[C2];
    int t = threadIdx.x;
    if (t < C2) {
        const float invN = 1.f/NVOX;
        float mean = sums[t]*invN;
        float var  = sums[C2+t]*invN - mean*mean;
        float sc = g[t]*rsqrtf(var + EPSBN);
        s_sc[t] = sc; s_sh[t] = be[t] - mean*sc;
    }
    __syncthreads();
    int i = blockIdx.x*256 + t;
    if (i >= NVOX*C2/4) return;
    const float4 v = *(const float4*)(y2 + (size_t)i*4);
    int c0 = (i*4) & (C2-1);
    ushort4 o;
    o.x = f2bf(fmaxf(0.f, v.x*s_sc[c0+0]+s_sh[c0+0]));
    o.y = f2bf(fmaxf(0.f, v.y*s_sc[c0+1]+s_sh[c0+1]));
    o.z = f2bf(fmaxf(0.f, v.z*s_sc[c0+2]+s_sh[c0+2]));
    o.w = f2bf(fmaxf(0.f, v.w*s_sc[c0+3]+s_sh[c0+3]));
    *(ushort4*)(f2b + (size_t)i*4) = o;
}

// ---------------- MFMA implicit-GEMM conv3d, stride 2, pad 1, k=3 ----------
// 256 thr = 4 waves (2 co x 2 sp). Block tile CO_T x 64 sp. Barrier-free tap
// loop with depth-4 rolling A-frag prefetch from global (L2-resident weights).
// GATHER: stage via winner (LDS-cached) + f2b gather. BNSTAGE: BN+relu applied
// while staging input. ATOMIC: split-K fp32 atomic output (conv3).
template<int CI, int CO, int CO_T, int DI, int HI, int WI, int DO, int HO, int WO,
         int NSLICE, bool GATHER, bool BNSTAGE, bool ATOMIC>
__global__ __launch_bounds__(256, 2) void conv3d_mfma(
        const ushortT* __restrict__ in_cl, const int* __restrict__ winner,
        const ushortT* __restrict__ wb, void* __restrict__ outp,
        float* __restrict__ sums_out,
        const float* __restrict__ bn_sums, const float* __restrict__ bn_g,
        const float* __restrict__ bn_be, float bn_invN) {
    constexpr int NCIG   = CI/32;
    constexpr int NCOG   = CO/16;
    constexpr int FRAG_M = CO_T/32;
    constexpr int CPB    = NCIG/NSLICE;
    __shared__ ushortT s_in[867*40];            // 3*17*17 pos x (32 ci, stride 40)
    __shared__ int     s_wn[GATHER ? 867 : 1];
    __shared__ float   s_sc[BNSTAGE ? CI : 1];
    __shared__ float   s_sh[BNSTAGE ? CI : 1];

    constexpr int nbx = WO/8, nby = HO/8;
    int b = blockIdx.x;
    const int bx = b % nbx; b /= nbx;
    const int by = b % nby; b /= nby;
    const int bz = b % DO;  b /= DO;
    const int cob   = b % (CO/CO_T);
    const int slice = b / (CO/CO_T);
    const int co0 = cob*CO_T;
    const int oy0 = by*8, ox0 = bx*8;
    const int t = threadIdx.x;
    const int lane = t & 63, wid = t >> 6;
    const int lr = lane & 15, lq = lane >> 4;
    const int wm = wid & 1, wn = wid >> 1;
    const int cog0 = (co0 + wm*(CO_T/2)) >> 4;

    if constexpr (BNSTAGE) {
        for (int c = t; c < CI; c += 256) {
            float mean = bn_sums[c]*bn_invN;
            float var  = bn_sums[CI+c]*bn_invN - mean*mean;
            float sc = bn_g[c]*rsqrtf(var + EPSBN);
            s_sc[c] = sc; s_sh[c] = bn_be[c] - mean*sc;
        }
    }
    if constexpr (GATHER) {
        for (int c = t; c < 867; c += 256) {
            int zz = c/289, rr = c - zz*289, yy = rr/17, xx = rr - yy*17;
            int iz = 2*bz-1+zz, iy = 2*oy0-1+yy, ix = 2*ox0-1+xx;
            int wv = -1;
            if ((unsigned)iz < (unsigned)DI && (unsigned)iy < (unsigned)HI &&
                (unsigned)ix < (unsigned)WI)
                wv = winner[(iz*HI + iy)*WI + ix];
            s_wn[c] = wv;
        }
    }

    int bbase[2];
    #pragma unroll
    for (int fn = 0; fn < 2; ++fn) {
        int n = wn*32 + fn*16 + lr;
        int oy = n >> 3, ox = n & 7;
        bbase[fn] = ((2*oy)*17 + 2*ox)*40 + lq*8;
    }

    f32x4 acc[FRAG_M][2];
    #pragma unroll
    for (int i = 0; i < FRAG_M; ++i)
        #pragma unroll
        for (int j = 0; j < 2; ++j) acc[i][j] = (f32x4){0.f,0.f,0.f,0.f};

    for (int cig = slice*CPB; cig < slice*CPB + CPB; ++cig) {
        __syncthreads();   // protect s_in / s_wn readiness
        const ushortT* wcig = wb + (((size_t)cig*27*NCOG) << 9) + (lane << 3);
        // depth-4 A-frag preload (in flight during staging)
        bf16x8 ap[4][FRAG_M];
        #pragma unroll
        for (int p = 0; p < 4; ++p)
            #pragma unroll
            for (int fm = 0; fm < FRAG_M; ++fm)
                ap[p][fm] = *(const bf16x8*)(wcig + ((p*NCOG + cog0 + fm) << 9));

        float scr[8], shr[8];
        if constexpr (BNSTAGE) {
            int ch0 = cig*32 + (t&3)*8;
            #pragma unroll
            for (int j = 0; j < 8; ++j) { scr[j] = s_sc[ch0+j]; shr[j] = s_sh[ch0+j]; }
        }
        for (int c = t; c < 3468; c += 256) {
            int pos = c >> 2, sub = c & 3;
            int4 v = {0,0,0,0};
            if constexpr (GATHER) {
                int w_ = s_wn[pos];
                if (w_ >= 0)
                    v = *(const int4*)(in_cl + (size_t)w_*CI + cig*32 + sub*8);
            } else {
                int zz = pos/289, rr = pos - zz*289, yy = rr/17, xx = rr - yy*17;
                int iz = 2*bz-1+zz, iy = 2*oy0-1+yy, ix = 2*ox0-1+xx;
                if ((unsigned)iz < (unsigned)DI && (unsigned)iy < (unsigned)HI &&
                    (unsigned)ix < (unsigned)WI) {
                    v = *(const int4*)(in_cl + ((size_t)(iz*HI + iy)*WI + ix)*CI
                                             + cig*32 + sub*8);
                    if constexpr (BNSTAGE) {
                        ushortT* u = (ushortT*)&v;
                        #pragma unroll
                        for (int j = 0; j < 8; ++j)
                            u[j] = f2bf(fmaxf(0.f, bf2f(u[j])*scr[j] + shr[j]));
                    }
                }
            }
            *(int4*)(s_in + pos*40 + sub*8) = v;
        }
        __syncthreads();

        #pragma unroll
        for (int tap = 0; tap < 27; ++tap) {
            const int kz = tap/9, ky = (tap/3)%3, kx = tap%3;
            const int toff = (kz*289 + ky*17 + kx)*40;
            bf16x8 bfr0 = *(const bf16x8*)(s_in + bbase[0] + toff);
            bf16x8 bfr1 = *(const bf16x8*)(s_in + bbase[1] + toff);
            const int slot = tap & 3;
            #pragma unroll
            for (int fm = 0; fm < FRAG_M; ++fm) {
                bf16x8 a = ap[slot][fm];
                if (tap + 4 < 27)
                    ap[slot][fm] = *(const bf16x8*)(wcig + (((tap+4)*NCOG + cog0 + fm) << 9));
                acc[fm][0] = __builtin_amdgcn_mfma_f32_16x16x32_bf16(a, bfr0, acc[fm][0], 0,0,0);
                acc[fm][1] = __builtin_amdgcn_mfma_f32_16x16x32_bf16(a, bfr1, acc[fm][1], 0,0,0);
            }
        }
    }

    if constexpr (!ATOMIC) {
        ushortT* out = (ushortT*)outp;
        #pragma unroll
        for (int fm = 0; fm < FRAG_M; ++fm)
        #pragma unroll
        for (int fn = 0; fn < 2; ++fn) {
            int n = wn*32 + fn*16 + lr;
            int oy = n >> 3, ox = n & 7;
            size_t sp = ((size_t)bz*HO + oy0+oy)*WO + ox0+ox;
            int c_ = co0 + wm*(CO_T/2) + fm*16 + lq*4;
            ushort4 o;
            o.x = f2bf(acc[fm][fn][0]); o.y = f2bf(acc[fm][fn][1]);
            o.z = f2bf(acc[fm][fn][2]); o.w = f2bf(acc[fm][fn][3]);
            *(ushort4*)(out + sp*CO + c_) = o;
        }
        // fused BN stats on fp32 accumulators
        #pragma unroll
        for (int fm = 0; fm < FRAG_M; ++fm) {
            float s[4], q[4];
            #pragma unroll
            for (int r = 0; r < 4; ++r) {
                float a0 = acc[fm][0][r], a1 = acc[fm][1][r];
                s[r] = a0 + a1; q[r] = a0*a0 + a1*a1;
                #pragma unroll
                for (int m = 1; m < 16; m <<= 1) {
                    s[r] += __shfl_xor(s[r], m, 64);
                    q[r] += __shfl_xor(q[r], m, 64);
                }
            }
            if (lr == 0) {
                int c_ = co0 + wm*(CO_T/2) + fm*16 + lq*4;
                #pragma unroll
                for (int r = 0; r < 4; ++r) {
                    atomicAdd(&sums_out[c_+r], s[r]);
                    atomicAdd(&sums_out[CO + c_+r], q[r]);
                }
            }
        }
    } else {
        float* out = (float*)outp;
        #pragma unroll
        for (int fm = 0; fm < FRAG_M; ++fm)
        #pragma unroll
        for (int fn = 0; fn < 2; ++fn) {
            int n = wn*32 + fn*16 + lr;
            int oy = n >> 3, ox = n & 7;
            int c_ = co0 + wm*(CO_T/2) + fm*16 + lq*4;
            #pragma unroll
            for (int r = 0; r < 4; ++r)
                atomicAdd(&out[((size_t)(c_+r)*DO + bz)*(HO*WO) + (oy0+oy)*WO + ox0+ox],
                          acc[fm][fn][r]);
        }
    }
}

// ---------------- BN for channel-major fp32 (final output) -----------------
template<int SPL>
__global__ void bn_stats_cmajor(const float* __restrict__ y, const float* __restrict__ g,
                                const float* __restrict__ be, float* __restrict__ ss, int C) {
    __shared__ float s_red[2][256];
    int c = blockIdx.x;
    const float* p = y + (size_t)c*SPL;
    float sum = 0.f, sq = 0.f;
    for (int i = threadIdx.x; i < SPL; i += 256) { float v = p[i]; sum += v; sq += v*v; }
    s_red[0][threadIdx.x] = sum; s_red[1][threadIdx.x] = sq;
    __syncthreads();
    for (int s = 128; s > 0; s >>= 1) {
        if (threadIdx.x < s) {
            s_red[0][threadIdx.x] += s_red[0][threadIdx.x+s];
            s_red[1][threadIdx.x] += s_red[1][threadIdx.x+s];
        }
        __syncthreads();
    }
    if (threadIdx.x == 0) {
        float invN = 1.f/(float)SPL;
        float mean = s_red[0][0]*invN;
        float var  = s_red[1][0]*invN - mean*mean;
        float sc = g[c]*rsqrtf(var + EPSBN);
        ss[c] = sc; ss[C+c] = be[c] - mean*sc;
    }
}

template<int LOGSPL>
__global__ void bn_apply_cmajor(float* __restrict__ y, const float* __restrict__ ss,
                                int C, int total) {
    for (int i = blockIdx.x*blockDim.x + threadIdx.x; i < total; i += gridDim.x*blockDim.x) {
        int c = i >> LOGSPL;
        y[i] = fmaxf(0.f, y[i]*ss[c] + ss[C+c]);
    }
}

// ---------------- host launcher --------------------------------------------
extern "C" void kernel_launch(void* const* d_in, const int* in_sizes, int n_in,
                              void* d_out, int out_size, void* d_ws, size_t ws_size,
                              hipStream_t stream) {
    const float* x      = (const float*)d_in[0];
    const int*   coords = (const int*)  d_in[1];
    const float* w1  = (const float*)d_in[5];
    const float* g1  = (const float*)d_in[7];
    const float* be1 = (const float*)d_in[8];
    const float* w2  = (const float*)d_in[9];
    const float* g2  = (const float*)d_in[11];
    const float* be2 = (const float*)d_in[12];
    const float* cw1 = (const float*)d_in[13];
    const float* cg1 = (const float*)d_in[15];
    const float* cbe1= (const float*)d_in[16];
    const float* cw2 = (const float*)d_in[17];
    const float* cg2 = (const float*)d_in[19];
    const float* cbe2= (const float*)d_in[20];
    const float* cw3 = (const float*)d_in[21];
    const float* cg3 = (const float*)d_in[23];
    const float* cbe3= (const float*)d_in[24];
    float* out = (float*)d_out;

    // ---- workspace layout ----
    float*   ws     = (float*)d_ws;
    float*   stats  = ws;                                   // 4096 f32
    int*     winner = (int*)(ws + 4096);                    // SP
    ushortT* f2b    = (ushortT*)(winner + SP);              // 12000*128
    float*   f1     = (float*)(f2b + (size_t)NVOX*C2);      // 12000*64
    float*   y2     = f1 + (size_t)NVOX*C1;                 // 12000*128
    ushortT* c1o    = (ushortT*)(y2 + (size_t)NVOX*C2);     // 32768*128
    ushortT* c2o    = c1o + (size_t)32768*128;              // 4096*256
    ushortT* wb1    = c2o + (size_t)4096*256;               // 442368
    ushortT* wb2    = wb1 + 442368;                         // 884736
    ushortT* wb3    = wb2 + 884736;                         // 1769472

    float* s1sum = stats;          // 128 (64 sum + 64 sq)
    float* s2sum = stats + 128;    // 256
    float* c1sum = stats + 384;    // 256
    float* c2sum = stats + 640;    // 512
    float* ss3   = stats + 1152;   // 512

    hipMemsetAsync(stats, 0, 4096*sizeof(float), stream);
    hipMemsetAsync(winner, 0xFF, SP*sizeof(int), stream);
    hipMemsetAsync(d_out, 0, (size_t)out_size*sizeof(float), stream);

    // prep: vfe1 stats (960) + weight convert (1024) + scatter (47)
    prep<<<2031, 256, 0, stream>>>(x, w1, s1sum, cw1, cw2, cw3, wb1, wb2, wb3,
                                   coords, winner);

    vfe1_apply<<<NVOX, 64, 0, stream>>>(x, w1, s1sum, g1, be1, f1);
    vfe2_linear<<<NVOX/16, 128, 0, stream>>>(f1, w2, y2, s2sum);
    vfe2_apply_bf16<<<NVOX*C2/4/256, 256, 0, stream>>>(y2, s2sum, g2, be2, f2b);

    // conv1: 128->128, (16,128,128)->(8,64,64); gather via winner, raw bf16 out
    conv3d_mfma<128,128,128, 16,128,128, 8,64,64, 1, true, false, false>
        <<<8*8*8, 256, 0, stream>>>(f2b, winner, wb1, c1o, c1sum,
                                    nullptr, nullptr, nullptr, 0.f);
    // conv2: 128->256, (8,64,64)->(4,32,32); BN1 applied on stage, raw bf16 out
    conv3d_mfma<128,256,64, 8,64,64, 4,32,32, 1, false, true, false>
        <<<4*4*4*4, 256, 0, stream>>>(c1o, nullptr, wb2, c2o, c2sum,
                                      c1sum, cg1, cbe1, 1.f/32768.f);
    // conv3: 256->256, (4,32,32)->(2,16,16); BN2 on stage, split-K x8 atomic out
    conv3d_mfma<256,256,64, 4,32,32, 2,16,16, 8, false, true, true>
        <<<2*2*2*4*8, 256, 0, stream>>>(c2o, nullptr, wb3, (void*)out, nullptr,
                                        c2sum, cg2, cbe2, 1.f/4096.f);

    bn_stats_cmajor<2*16*16><<<256, 256, 0, stream>>>(out, cg3, cbe3, ss3, 256);
    bn_apply_cmajor<9><<<512, 256, 0, stream>>>(out, ss3, 256, 131072);
}